// Round 2
// baseline (190.283 us; speedup 1.0000x reference)
//
#include <hip/hip_runtime.h>
#include <hip/hip_bf16.h>
#include <cstddef>

#define NE 65536
#define ND 256
#define NP 8
#define CAP 16384            // per-expert perm capacity (mean count 8192)
#define TMAX 256             // CAP/64 tiles per expert

typedef short bf16x8 __attribute__((ext_vector_type(8)));
typedef float f32x4  __attribute__((ext_vector_type(4)));

__device__ __forceinline__ unsigned short f2bf(float f) {
  unsigned int u = __float_as_uint(f);
  u += 0x7FFFu + ((u >> 16) & 1u);   // round-to-nearest-even
  return (unsigned short)(u >> 16);
}

// ---- detect idx dtype: if all odd 32-bit words of the first NE words are 0,
// the buffer is int64 (values < 8 so high words are 0). Safe to read NE words
// under both interpretations (int32: exactly the buffer; int64: first half).
__global__ __launch_bounds__(256) void k_detect(const unsigned int* __restrict__ w,
                                                int* __restrict__ flag) {
  int t = blockIdx.x * 256 + threadIdx.x;   // 64 blocks x 256 = 16384 threads
  unsigned int acc = 0;
#pragma unroll
  for (int i = 0; i < 2; ++i) {
    int odd = (t + i * 16384) * 2 + 1;      // odd word indices < NE
    acc |= w[odd];
  }
  // wave-reduce then one atomic per wave
  for (int d = 1; d < 64; d <<= 1) acc |= (unsigned int)__shfl_xor((int)acc, d, 64);
  if ((threadIdx.x & 63) == 0 && acc) atomicOr(flag, 1);
}

// ---- prep: W_bil -> B-frag bf16 layout; v_p = b_lr[p] @ W_bil (fp32) ----
// Frag layout (for mfma_f32_16x16x32_bf16 B operand):
//   store[((kt*16 + c)*64 + l)*8 + j] = M[kt*32 + (l>>4)*8 + j][c*16 + (l&15)]
__global__ __launch_bounds__(256) void k_prep(const float* __restrict__ Wbil,
                                              const float* __restrict__ blr,
                                              unsigned short* __restrict__ WbT,
                                              float* __restrict__ v) {
  int b = blockIdx.x, t = threadIdx.x;
  if (b < 32) {
    int s = b * 256 + t;                 // slot 0..8191
    int kt = s >> 10, c = (s >> 6) & 15, l = s & 63;
    int col = c * 16 + (l & 15);
    int k0 = kt * 32 + (l >> 4) * 8;
    union { uint4 u; unsigned short h[8]; } uu;
#pragma unroll
    for (int j = 0; j < 8; ++j)
      uu.h[j] = f2bf(Wbil[(k0 + j) * ND + col]);
    *(uint4*)(WbT + (size_t)s * 8) = uu.u;
  } else {
    int p = b - 32;
    float s = 0.f;
    for (int k = 0; k < ND; ++k)
      s = fmaf(blr[p * ND + k], Wbil[k * ND + t], s);
    v[p * ND + t] = s;
  }
}

// ---- route: scatter edge ids into per-expert buckets (wave-aggregated atomics)
__global__ __launch_bounds__(256) void k_route(const void* __restrict__ idxraw,
                                               const int* __restrict__ flag,
                                               int* __restrict__ cursor,
                                               int* __restrict__ perm) {
  int e = blockIdx.x * 256 + threadIdx.x;
  int is32 = *flag;                        // uniform
  int p = is32 ? ((const int*)idxraw)[e]
               : (int)((const long long*)idxraw)[e];
  int lane = threadIdx.x & 63;
  unsigned long long lt = (1ull << lane) - 1ull;
  for (int q = 0; q < NP; ++q) {
    unsigned long long m = __ballot(p == q);
    if (m == 0ull) continue;
    int leader = __ffsll((unsigned long long)m) - 1;
    int wbase = 0;
    if (lane == leader) wbase = atomicAdd(&cursor[q], __popcll(m));
    wbase = __shfl(wbase, leader, 64);
    if (p == q)
      perm[q * CAP + wbase + __popcll(m & lt)] = e;
  }
}

// ---- C_p = W_lr[p]^T @ W_bil  (bf16 MFMA), written in B-frag layout ----
__global__ __launch_bounds__(256) void k_cpre(const float* __restrict__ Wlr,
                                              const unsigned short* __restrict__ WbT,
                                              unsigned short* __restrict__ Cst) {
  __shared__ unsigned short aF[2048 * 8];      // 32 KiB: A-frag layout
  int blk = blockIdx.x;
  int p = blk >> 2;
  int i0 = (blk & 3) * 64;
  int tid = threadIdx.x;
  const float* Wp = Wlr + (size_t)p * ND * ND;
#pragma unroll
  for (int it = 0; it < 8; ++it) {
    int s = tid + it * 256;                    // slot = ((kt*4 + r)*64 + l)
    int kt = s >> 8, r = (s >> 6) & 3, l = s & 63;
    int i = r * 16 + (l & 15);
    int k0 = kt * 32 + (l >> 4) * 8;
    union { uint4 u; unsigned short h[8]; } uu;
#pragma unroll
    for (int j = 0; j < 8; ++j)                // A[i][k] = Wlr[p][k][i0+i]
      uu.h[j] = f2bf(Wp[(size_t)(k0 + j) * ND + i0 + i]);
    *(uint4*)(aF + (size_t)s * 8) = uu.u;
  }
  __syncthreads();
  int w = tid >> 6, l = tid & 63;
  f32x4 zero = {0.f, 0.f, 0.f, 0.f};
  f32x4 acc[16];
#pragma unroll
  for (int c = 0; c < 16; ++c) acc[c] = zero;
  for (int kt = 0; kt < 8; ++kt) {
    bf16x8 a = *(const bf16x8*)(aF + (size_t)((kt * 4 + w) * 64 + l) * 8);
#pragma unroll
    for (int c = 0; c < 16; ++c) {
      bf16x8 bb = *(const bf16x8*)(WbT + (size_t)((kt * 16 + c) * 64 + l) * 8);
      acc[c] = __builtin_amdgcn_mfma_f32_16x16x32_bf16(a, bb, acc[c], 0, 0, 0);
    }
  }
  // lane holds C[i][j], i = i0 + w*16 + (l>>4)*4 + q, j = c*16 + (l&15)
  unsigned short* Cp = Cst + (size_t)p * ND * ND;
#pragma unroll
  for (int c = 0; c < 16; ++c) {
#pragma unroll
    for (int q = 0; q < 4; ++q) {
      int i = i0 + w * 16 + ((l >> 4) * 4) + q;
      int j = c * 16 + (l & 15);
      // B-frag position for k_main (k-dim = i, n-dim = j):
      int pos = ((i >> 5) * 16 + (j >> 4)) * 512 + (((i >> 3) & 3) * 16 + (j & 15)) * 8 + (i & 7);
      Cp[pos] = f2bf(acc[c][q]);
    }
  }
}

// ---- main: per 64-row tile of one expert: t = z_src@C_p ; score = (t+v_p)·z_dst + b
__global__ __launch_bounds__(256) void k_main(const float* __restrict__ zsrc,
                                              const float* __restrict__ zdst,
                                              const int* __restrict__ perm,
                                              const int* __restrict__ cursor,
                                              const unsigned short* __restrict__ Cst,
                                              const float* __restrict__ v,
                                              const float* __restrict__ bbil,
                                              float* __restrict__ out) {
  int p = blockIdx.x >> 8;                     // TMAX = 256
  int t = blockIdx.x & 255;
  int cnt = cursor[p];
  if (t * 64 >= cnt) return;
  __shared__ unsigned short aF[2048 * 8];      // 32 KiB A-frag tile
  __shared__ int eids[64];
  __shared__ float red[4][64];
  int tid = threadIdx.x;
  if (tid < 64) {
    int r = t * 64 + tid;
    eids[tid] = perm[p * CAP + (r < cnt ? r : cnt - 1)];
  }
  __syncthreads();
#pragma unroll
  for (int it = 0; it < 8; ++it) {
    int s = tid + it * 256;
    int kt = s >> 8, rr = (s >> 6) & 3, l = s & 63;
    int row = rr * 16 + (l & 15);
    int k0 = kt * 32 + (l >> 4) * 8;
    const float* src = zsrc + (size_t)eids[row] * ND + k0;
    float f[8];
    *(float4*)(f)     = *(const float4*)(src);
    *(float4*)(f + 4) = *(const float4*)(src + 4);
    union { uint4 u; unsigned short h[8]; } uu;
#pragma unroll
    for (int j = 0; j < 8; ++j) uu.h[j] = f2bf(f[j]);
    *(uint4*)(aF + (size_t)s * 8) = uu.u;
  }
  __syncthreads();
  int w = tid >> 6, l = tid & 63;
  const unsigned short* Cp = Cst + (size_t)p * ND * ND;
  f32x4 zero = {0.f, 0.f, 0.f, 0.f};
  f32x4 acc[4][4];                             // [row-strip][local col-tile]
#pragma unroll
  for (int r = 0; r < 4; ++r)
#pragma unroll
    for (int c = 0; c < 4; ++c) acc[r][c] = zero;
  for (int kt = 0; kt < 8; ++kt) {
    bf16x8 a[4];
#pragma unroll
    for (int r = 0; r < 4; ++r)
      a[r] = *(const bf16x8*)(aF + (size_t)((kt * 4 + r) * 64 + l) * 8);
#pragma unroll
    for (int cl = 0; cl < 4; ++cl) {
      int c = w * 4 + cl;
      bf16x8 bb = *(const bf16x8*)(Cp + (size_t)((kt * 16 + c) * 64 + l) * 8);
#pragma unroll
      for (int r = 0; r < 4; ++r)
        acc[r][cl] = __builtin_amdgcn_mfma_f32_16x16x32_bf16(a[r], bb, acc[r][cl], 0, 0, 0);
    }
  }
  // fused epilogue: score_row = sum_col (t[row][col] + v_p[col]) * zdst[e_row][col]
  float vloc[4];
#pragma unroll
  for (int cl = 0; cl < 4; ++cl)
    vloc[cl] = v[p * ND + (w * 4 + cl) * 16 + (l & 15)];
#pragma unroll
  for (int r = 0; r < 4; ++r) {
#pragma unroll
    for (int q = 0; q < 4; ++q) {
      int row = r * 16 + ((l >> 4) * 4) + q;   // D-layout: col=l&15, row=(l>>4)*4+reg
      const float* drow = zdst + (size_t)eids[row] * ND;
      float sv = 0.f;
#pragma unroll
      for (int cl = 0; cl < 4; ++cl) {
        int col = (w * 4 + cl) * 16 + (l & 15);
        sv = fmaf(acc[r][cl][q] + vloc[cl], drow[col], sv);
      }
      sv += __shfl_xor(sv, 1, 64);
      sv += __shfl_xor(sv, 2, 64);
      sv += __shfl_xor(sv, 4, 64);
      sv += __shfl_xor(sv, 8, 64);
      if ((l & 15) == 0) red[w][row] = sv;
    }
  }
  __syncthreads();
  if (tid < 64) {
    int gr = t * 64 + tid;
    if (gr < cnt) {
      float sc = red[0][tid] + red[1][tid] + red[2][tid] + red[3][tid] + bbil[0];
      out[eids[tid]] = sc;
    }
  }
}

extern "C" void kernel_launch(void* const* d_in, const int* in_sizes, int n_in,
                              void* d_out, int out_size, void* d_ws, size_t ws_size,
                              hipStream_t stream) {
  // setup_inputs() dict order: z_src, z_dst, W_lr, b_lr, W_bil, b_bil, lr_pair_idx
  const float* zsrc = (const float*)d_in[0];
  const float* zdst = (const float*)d_in[1];
  const float* Wlr  = (const float*)d_in[2];
  const float* blr  = (const float*)d_in[3];
  const float* Wbil = (const float*)d_in[4];
  const float* bbil = (const float*)d_in[5];
  const void*  idx  = (const void*)d_in[6];   // int32 or int64 — detected on device
  float* out = (float*)d_out;

  char* ws = (char*)d_ws;
  int* cursor = (int*)ws;                                            // 8 x int
  int* flag   = (int*)(ws + 32);                                     // dtype flag
  int* perm = (int*)(ws + 1024);                                     // 512 KiB
  unsigned short* WbT = (unsigned short*)(ws + 1024 + (size_t)NP * CAP * 4);          // 128 KiB
  float* v = (float*)(ws + 1024 + (size_t)NP * CAP * 4 + 131072);                     // 8 KiB
  unsigned short* Cst = (unsigned short*)(ws + 1024 + (size_t)NP * CAP * 4 + 131072 + 8192); // 1 MiB

  hipMemsetAsync(ws, 0, 64, stream);
  k_detect<<<64, 256, 0, stream>>>((const unsigned int*)idx, flag);
  k_prep<<<40, 256, 0, stream>>>(Wbil, blr, WbT, v);
  k_route<<<NE / 256, 256, 0, stream>>>(idx, flag, cursor, perm);
  k_cpre<<<32, 256, 0, stream>>>(Wlr, WbT, Cst);
  k_main<<<NP * TMAX, 256, 0, stream>>>(zsrc, zdst, perm, cursor, Cst, v, bbil, out);
}

// Round 3
// 102.276 us; speedup vs baseline: 1.8605x; 1.8605x over previous
//
#include <hip/hip_runtime.h>
#include <hip/hip_bf16.h>
#include <cstddef>

#define NE 65536
#define ND 256
#define NP 8
#define CAP 16384            // per-expert perm capacity
#define TMAX 256             // CAP/64 tiles per expert
#define RBLK 64              // routing blocks
#define EPB (NE / RBLK)      // 1024 edges per routing block

typedef short bf16x8 __attribute__((ext_vector_type(8)));
typedef float f32x4  __attribute__((ext_vector_type(4)));

__device__ __forceinline__ unsigned short f2bf(float f) {
  unsigned int u = __float_as_uint(f);
  u += 0x7FFFu + ((u >> 16) & 1u);   // round-to-nearest-even
  return (unsigned short)(u >> 16);
}

// ---- detect idx dtype: all odd 32-bit words of first NE words zero => int64
__global__ __launch_bounds__(256) void k_detect(const unsigned int* __restrict__ w,
                                                int* __restrict__ flag) {
  int t = blockIdx.x * 256 + threadIdx.x;   // 64 x 256 = 16384 threads
  unsigned int acc = 0;
#pragma unroll
  for (int i = 0; i < 2; ++i) {
    int odd = (t + i * 16384) * 2 + 1;
    acc |= w[odd];
  }
  for (int d = 1; d < 64; d <<= 1) acc |= (unsigned int)__shfl_xor((int)acc, d, 64);
  if ((threadIdx.x & 63) == 0 && acc) atomicOr(flag, 1);
}

__device__ __forceinline__ int load_idx(const void* idxraw, int is32, int e) {
  return is32 ? ((const int*)idxraw)[e] : (int)((const long long*)idxraw)[e];
}

// ---- phase 1: per-block LDS histogram (no global atomics) ----
__global__ __launch_bounds__(256) void k_hist(const void* __restrict__ idxraw,
                                              const int* __restrict__ flag,
                                              int* __restrict__ counts) {
  __shared__ int h[NP];
  int tid = threadIdx.x;
  if (tid < NP) h[tid] = 0;
  __syncthreads();
  int is32 = *flag;
  int base = blockIdx.x * EPB;
#pragma unroll
  for (int i = 0; i < EPB / 256; ++i) {
    int p = load_idx(idxraw, is32, base + tid + i * 256);
    atomicAdd(&h[p], 1);                       // LDS atomic
  }
  __syncthreads();
  if (tid < NP) counts[blockIdx.x * NP + tid] = h[tid];
}

// ---- phase 2: exclusive scan over blocks per expert; totals -> cursor ----
__global__ __launch_bounds__(64) void k_scan(const int* __restrict__ counts,
                                             int* __restrict__ bases,
                                             int* __restrict__ cursor) {
  int q = threadIdx.x;
  if (q < NP) {
    int run = 0;
    for (int b = 0; b < RBLK; ++b) {
      bases[b * NP + q] = run;
      run += counts[b * NP + q];
    }
    cursor[q] = run;
  }
}

// ---- phase 3: scatter with LDS cursors seeded from bases ----
__global__ __launch_bounds__(256) void k_scatter(const void* __restrict__ idxraw,
                                                 const int* __restrict__ flag,
                                                 const int* __restrict__ bases,
                                                 int* __restrict__ perm) {
  __shared__ int cur[NP];
  int tid = threadIdx.x;
  if (tid < NP) cur[tid] = bases[blockIdx.x * NP + tid];
  __syncthreads();
  int is32 = *flag;
  int base = blockIdx.x * EPB;
#pragma unroll
  for (int i = 0; i < EPB / 256; ++i) {
    int e = base + tid + i * 256;
    int p = load_idx(idxraw, is32, e);
    int slot = atomicAdd(&cur[p], 1);          // LDS atomic
    perm[p * CAP + slot] = e;
  }
}

// ---- prep: W_bil -> B-frag bf16 layout; v_p = b_lr[p] @ W_bil (fp32) ----
__global__ __launch_bounds__(256) void k_prep(const float* __restrict__ Wbil,
                                              const float* __restrict__ blr,
                                              unsigned short* __restrict__ WbT,
                                              float* __restrict__ v) {
  int b = blockIdx.x, t = threadIdx.x;
  if (b < 32) {
    int s = b * 256 + t;                 // slot 0..8191
    int kt = s >> 10, c = (s >> 6) & 15, l = s & 63;
    int col = c * 16 + (l & 15);
    int k0 = kt * 32 + (l >> 4) * 8;
    union { uint4 u; unsigned short h[8]; } uu;
#pragma unroll
    for (int j = 0; j < 8; ++j)
      uu.h[j] = f2bf(Wbil[(k0 + j) * ND + col]);
    *(uint4*)(WbT + (size_t)s * 8) = uu.u;
  } else {
    int p = b - 32;
    float s = 0.f;
    for (int k = 0; k < ND; ++k)
      s = fmaf(blr[p * ND + k], Wbil[k * ND + t], s);
    v[p * ND + t] = s;
  }
}

// ---- C_p = W_lr[p]^T @ W_bil  (bf16 MFMA), written in B-frag layout ----
__global__ __launch_bounds__(256) void k_cpre(const float* __restrict__ Wlr,
                                              const unsigned short* __restrict__ WbT,
                                              unsigned short* __restrict__ Cst) {
  __shared__ unsigned short aF[2048 * 8];      // 32 KiB
  int blk = blockIdx.x;
  int p = blk >> 2;
  int i0 = (blk & 3) * 64;
  int tid = threadIdx.x;
  const float* Wp = Wlr + (size_t)p * ND * ND;
#pragma unroll
  for (int it = 0; it < 8; ++it) {
    int s = tid + it * 256;                    // slot = ((kt*4 + r)*64 + l)
    int kt = s >> 8, r = (s >> 6) & 3, l = s & 63;
    int i = r * 16 + (l & 15);
    int k0 = kt * 32 + (l >> 4) * 8;
    union { uint4 u; unsigned short h[8]; } uu;
#pragma unroll
    for (int j = 0; j < 8; ++j)                // A[i][k] = Wlr[p][k][i0+i]
      uu.h[j] = f2bf(Wp[(size_t)(k0 + j) * ND + i0 + i]);
    *(uint4*)(aF + (size_t)s * 8) = uu.u;
  }
  __syncthreads();
  int w = tid >> 6, l = tid & 63;
  f32x4 zero = {0.f, 0.f, 0.f, 0.f};
  f32x4 acc[16];
#pragma unroll
  for (int c = 0; c < 16; ++c) acc[c] = zero;
  for (int kt = 0; kt < 8; ++kt) {
    bf16x8 a = *(const bf16x8*)(aF + (size_t)((kt * 4 + w) * 64 + l) * 8);
#pragma unroll
    for (int c = 0; c < 16; ++c) {
      bf16x8 bb = *(const bf16x8*)(WbT + (size_t)((kt * 16 + c) * 64 + l) * 8);
      acc[c] = __builtin_amdgcn_mfma_f32_16x16x32_bf16(a, bb, acc[c], 0, 0, 0);
    }
  }
  unsigned short* Cp = Cst + (size_t)p * ND * ND;
#pragma unroll
  for (int c = 0; c < 16; ++c) {
#pragma unroll
    for (int q = 0; q < 4; ++q) {
      int i = i0 + w * 16 + ((l >> 4) * 4) + q;
      int j = c * 16 + (l & 15);
      int pos = ((i >> 5) * 16 + (j >> 4)) * 512 + (((i >> 3) & 3) * 16 + (j & 15)) * 8 + (i & 7);
      Cp[pos] = f2bf(acc[c][q]);
    }
  }
}

// ---- main: per 64-row tile of one expert: t = z_src@C_p ; score = (t+v_p)·z_dst + b
__global__ __launch_bounds__(256) void k_main(const float* __restrict__ zsrc,
                                              const float* __restrict__ zdst,
                                              const int* __restrict__ perm,
                                              const int* __restrict__ cursor,
                                              const unsigned short* __restrict__ Cst,
                                              const float* __restrict__ v,
                                              const float* __restrict__ bbil,
                                              float* __restrict__ out) {
  int p = blockIdx.x >> 8;                     // TMAX = 256
  int t = blockIdx.x & 255;
  int cnt = cursor[p];
  if (t * 64 >= cnt) return;
  __shared__ unsigned short aF[2048 * 8];      // 32 KiB
  __shared__ int eids[64];
  __shared__ float red[4][64];
  int tid = threadIdx.x;
  if (tid < 64) {
    int r = t * 64 + tid;
    eids[tid] = perm[p * CAP + (r < cnt ? r : cnt - 1)];
  }
  __syncthreads();
#pragma unroll
  for (int it = 0; it < 8; ++it) {
    int s = tid + it * 256;
    int kt = s >> 8, rr = (s >> 6) & 3, l = s & 63;
    int row = rr * 16 + (l & 15);
    int k0 = kt * 32 + (l >> 4) * 8;
    const float* src = zsrc + (size_t)eids[row] * ND + k0;
    float f[8];
    *(float4*)(f)     = *(const float4*)(src);
    *(float4*)(f + 4) = *(const float4*)(src + 4);
    union { uint4 u; unsigned short h[8]; } uu;
#pragma unroll
    for (int j = 0; j < 8; ++j) uu.h[j] = f2bf(f[j]);
    *(uint4*)(aF + (size_t)s * 8) = uu.u;
  }
  __syncthreads();
  int w = tid >> 6, l = tid & 63;
  const unsigned short* Cp = Cst + (size_t)p * ND * ND;
  f32x4 zero = {0.f, 0.f, 0.f, 0.f};
  f32x4 acc[4][4];
#pragma unroll
  for (int r = 0; r < 4; ++r)
#pragma unroll
    for (int c = 0; c < 4; ++c) acc[r][c] = zero;
  for (int kt = 0; kt < 8; ++kt) {
    bf16x8 a[4];
#pragma unroll
    for (int r = 0; r < 4; ++r)
      a[r] = *(const bf16x8*)(aF + (size_t)((kt * 4 + r) * 64 + l) * 8);
#pragma unroll
    for (int cl = 0; cl < 4; ++cl) {
      int c = w * 4 + cl;
      bf16x8 bb = *(const bf16x8*)(Cp + (size_t)((kt * 16 + c) * 64 + l) * 8);
#pragma unroll
      for (int r = 0; r < 4; ++r)
        acc[r][cl] = __builtin_amdgcn_mfma_f32_16x16x32_bf16(a[r], bb, acc[r][cl], 0, 0, 0);
    }
  }
  float vloc[4];
#pragma unroll
  for (int cl = 0; cl < 4; ++cl)
    vloc[cl] = v[p * ND + (w * 4 + cl) * 16 + (l & 15)];
#pragma unroll
  for (int r = 0; r < 4; ++r) {
#pragma unroll
    for (int q = 0; q < 4; ++q) {
      int row = r * 16 + ((l >> 4) * 4) + q;   // D-layout: col=l&15, row=(l>>4)*4+reg
      const float* drow = zdst + (size_t)eids[row] * ND;
      float sv = 0.f;
#pragma unroll
      for (int cl = 0; cl < 4; ++cl) {
        int col = (w * 4 + cl) * 16 + (l & 15);
        sv = fmaf(acc[r][cl][q] + vloc[cl], drow[col], sv);
      }
      sv += __shfl_xor(sv, 1, 64);
      sv += __shfl_xor(sv, 2, 64);
      sv += __shfl_xor(sv, 4, 64);
      sv += __shfl_xor(sv, 8, 64);
      if ((l & 15) == 0) red[w][row] = sv;
    }
  }
  __syncthreads();
  if (tid < 64) {
    int gr = t * 64 + tid;
    if (gr < cnt) {
      float sc = red[0][tid] + red[1][tid] + red[2][tid] + red[3][tid] + bbil[0];
      out[eids[tid]] = sc;
    }
  }
}

extern "C" void kernel_launch(void* const* d_in, const int* in_sizes, int n_in,
                              void* d_out, int out_size, void* d_ws, size_t ws_size,
                              hipStream_t stream) {
  // setup_inputs() dict order: z_src, z_dst, W_lr, b_lr, W_bil, b_bil, lr_pair_idx
  const float* zsrc = (const float*)d_in[0];
  const float* zdst = (const float*)d_in[1];
  const float* Wlr  = (const float*)d_in[2];
  const float* blr  = (const float*)d_in[3];
  const float* Wbil = (const float*)d_in[4];
  const float* bbil = (const float*)d_in[5];
  const void*  idx  = (const void*)d_in[6];   // int32 or int64 — detected on device
  float* out = (float*)d_out;

  char* ws = (char*)d_ws;
  int* cursor = (int*)ws;                                  // 32 B
  int* flag   = (int*)(ws + 64);                           // 4 B
  int* counts = (int*)(ws + 4096);                         // 2 KiB
  int* bases  = (int*)(ws + 8192);                         // 2 KiB
  int* perm   = (int*)(ws + 16384);                        // 512 KiB
  unsigned short* WbT = (unsigned short*)(ws + 16384 + (size_t)NP * CAP * 4);            // 128 KiB
  float* v = (float*)(ws + 16384 + (size_t)NP * CAP * 4 + 131072);                       // 8 KiB
  unsigned short* Cst = (unsigned short*)(ws + 16384 + (size_t)NP * CAP * 4 + 131072 + 8192); // 1 MiB

  hipMemsetAsync(ws, 0, 128, stream);
  k_detect<<<64, 256, 0, stream>>>((const unsigned int*)idx, flag);
  k_prep<<<40, 256, 0, stream>>>(Wbil, blr, WbT, v);
  k_hist<<<RBLK, 256, 0, stream>>>(idx, flag, counts);
  k_scan<<<1, 64, 0, stream>>>(counts, bases, cursor);
  k_scatter<<<RBLK, 256, 0, stream>>>(idx, flag, bases, perm);
  k_cpre<<<32, 256, 0, stream>>>(Wlr, WbT, Cst);
  k_main<<<NP * TMAX, 256, 0, stream>>>(zsrc, zdst, perm, cursor, Cst, v, bbil, out);
}

// Round 4
// 89.920 us; speedup vs baseline: 2.1161x; 1.1374x over previous
//
#include <hip/hip_runtime.h>
#include <hip/hip_bf16.h>
#include <cstddef>

#define NE 65536
#define ND 256
#define NP 8
#define CAP 16384            // per-expert perm capacity
#define TMAX 256             // CAP/64 tiles per expert
#define RBLK 64              // routing blocks
#define EPB (NE / RBLK)      // 1024 edges per routing block

typedef short bf16x8 __attribute__((ext_vector_type(8)));
typedef float f32x4  __attribute__((ext_vector_type(4)));

__device__ __forceinline__ unsigned short f2bf(float f) {
  unsigned int u = __float_as_uint(f);
  u += 0x7FFFu + ((u >> 16) & 1u);   // round-to-nearest-even
  return (unsigned short)(u >> 16);
}

// Per-block idx-dtype sniff: sample 256 odd 32-bit words from the first NE
// words. int64 buffer (values < 8) => all odd words 0. int32 => random idx
// values; P(256 samples all zero) = (1/8)^256 ~ 0. Returns is32 flag (LDS).
__device__ __forceinline__ int sniff_is32(const void* idxraw, int* lflag) {
  int tid = threadIdx.x;
  if (tid == 0) *lflag = 0;
  __syncthreads();
  const unsigned int* w = (const unsigned int*)idxraw;
  unsigned int val = w[(blockIdx.x * 256 + tid) * 2 + 1];   // word idx < 2*16384+1 < NE
  if (__any(val != 0) && (tid & 63) == 0) atomicOr(lflag, 1);
  __syncthreads();
  return *lflag;
}

__device__ __forceinline__ int load_idx(const void* idxraw, int is32, int e) {
  return is32 ? ((const int*)idxraw)[e] : (int)((const long long*)idxraw)[e];
}

// ---- phase 1: per-block LDS histogram (no global atomics) ----
__global__ __launch_bounds__(256) void k_hist(const void* __restrict__ idxraw,
                                              int* __restrict__ counts) {
  __shared__ int h[NP];
  __shared__ int lflag;
  int tid = threadIdx.x;
  int is32 = sniff_is32(idxraw, &lflag);
  if (tid < NP) h[tid] = 0;
  __syncthreads();
  int base = blockIdx.x * EPB;
#pragma unroll
  for (int i = 0; i < EPB / 256; ++i) {
    int p = load_idx(idxraw, is32, base + tid + i * 256);
    atomicAdd(&h[p], 1);                       // LDS atomic
  }
  __syncthreads();
  if (tid < NP) counts[blockIdx.x * NP + tid] = h[tid];
}

// ---- phase 2: exclusive scan over blocks per expert; totals -> cursor ----
__global__ __launch_bounds__(64) void k_scan(const int* __restrict__ counts,
                                             int* __restrict__ bases,
                                             int* __restrict__ cursor) {
  int q = threadIdx.x;
  if (q < NP) {
    int run = 0;
    for (int b = 0; b < RBLK; ++b) {
      bases[b * NP + q] = run;
      run += counts[b * NP + q];
    }
    cursor[q] = run;
  }
}

// ---- phase 3: scatter with LDS cursors seeded from bases ----
__global__ __launch_bounds__(256) void k_scatter(const void* __restrict__ idxraw,
                                                 const int* __restrict__ bases,
                                                 int* __restrict__ perm) {
  __shared__ int cur[NP];
  __shared__ int lflag;
  int tid = threadIdx.x;
  int is32 = sniff_is32(idxraw, &lflag);
  if (tid < NP) cur[tid] = bases[blockIdx.x * NP + tid];
  __syncthreads();
  int base = blockIdx.x * EPB;
#pragma unroll
  for (int i = 0; i < EPB / 256; ++i) {
    int e = base + tid + i * 256;
    int p = load_idx(idxraw, is32, e);
    int slot = atomicAdd(&cur[p], 1);          // LDS atomic
    perm[p * CAP + slot] = e;
  }
}

// ---- prep: W_bil -> B-frag bf16 layout; v_p = b_lr[p] @ W_bil (fp32) ----
__global__ __launch_bounds__(256) void k_prep(const float* __restrict__ Wbil,
                                              const float* __restrict__ blr,
                                              unsigned short* __restrict__ WbT,
                                              float* __restrict__ v) {
  int b = blockIdx.x, t = threadIdx.x;
  if (b < 32) {
    int s = b * 256 + t;                 // slot 0..8191
    int kt = s >> 10, c = (s >> 6) & 15, l = s & 63;
    int col = c * 16 + (l & 15);
    int k0 = kt * 32 + (l >> 4) * 8;
    union { uint4 u; unsigned short h[8]; } uu;
#pragma unroll
    for (int j = 0; j < 8; ++j)
      uu.h[j] = f2bf(Wbil[(k0 + j) * ND + col]);
    *(uint4*)(WbT + (size_t)s * 8) = uu.u;
  } else {
    int p = b - 32;
    float s = 0.f;
    for (int k = 0; k < ND; ++k)
      s = fmaf(blr[p * ND + k], Wbil[k * ND + t], s);
    v[p * ND + t] = s;
  }
}

// ---- C_p = W_lr[p]^T @ W_bil  (bf16 MFMA), written in B-frag layout ----
__global__ __launch_bounds__(256) void k_cpre(const float* __restrict__ Wlr,
                                              const unsigned short* __restrict__ WbT,
                                              unsigned short* __restrict__ Cst) {
  __shared__ unsigned short aF[2048 * 8];      // 32 KiB
  int blk = blockIdx.x;
  int p = blk >> 2;
  int i0 = (blk & 3) * 64;
  int tid = threadIdx.x;
  const float* Wp = Wlr + (size_t)p * ND * ND;
#pragma unroll
  for (int it = 0; it < 8; ++it) {
    int s = tid + it * 256;                    // slot = ((kt*4 + r)*64 + l)
    int kt = s >> 8, r = (s >> 6) & 3, l = s & 63;
    int i = r * 16 + (l & 15);
    int k0 = kt * 32 + (l >> 4) * 8;
    union { uint4 u; unsigned short h[8]; } uu;
#pragma unroll
    for (int j = 0; j < 8; ++j)                // A[i][k] = Wlr[p][k][i0+i]
      uu.h[j] = f2bf(Wp[(size_t)(k0 + j) * ND + i0 + i]);
    *(uint4*)(aF + (size_t)s * 8) = uu.u;
  }
  __syncthreads();
  int w = tid >> 6, l = tid & 63;
  f32x4 zero = {0.f, 0.f, 0.f, 0.f};
  f32x4 acc[16];
#pragma unroll
  for (int c = 0; c < 16; ++c) acc[c] = zero;
  for (int kt = 0; kt < 8; ++kt) {
    bf16x8 a = *(const bf16x8*)(aF + (size_t)((kt * 4 + w) * 64 + l) * 8);
#pragma unroll
    for (int c = 0; c < 16; ++c) {
      bf16x8 bb = *(const bf16x8*)(WbT + (size_t)((kt * 16 + c) * 64 + l) * 8);
      acc[c] = __builtin_amdgcn_mfma_f32_16x16x32_bf16(a, bb, acc[c], 0, 0, 0);
    }
  }
  unsigned short* Cp = Cst + (size_t)p * ND * ND;
#pragma unroll
  for (int c = 0; c < 16; ++c) {
#pragma unroll
    for (int q = 0; q < 4; ++q) {
      int i = i0 + w * 16 + ((l >> 4) * 4) + q;
      int j = c * 16 + (l & 15);
      int pos = ((i >> 5) * 16 + (j >> 4)) * 512 + (((i >> 3) & 3) * 16 + (j & 15)) * 8 + (i & 7);
      Cp[pos] = f2bf(acc[c][q]);
    }
  }
}

// ---- main: per 64-row tile: t = z_src@C_p ; score = (t+v_p)·z_dst + b ----
// zdst is staged into LDS (bf16, XOR-swizzled) during phase 1 so the epilogue
// has no global latency; launch_bounds(256,2) frees the register budget so
// the compiler pipelines the Cst (L2) loads across the kt loop.
__global__ __launch_bounds__(256, 2) void k_main(const float* __restrict__ zsrc,
                                                 const float* __restrict__ zdst,
                                                 const int* __restrict__ perm,
                                                 const int* __restrict__ cursor,
                                                 const unsigned short* __restrict__ Cst,
                                                 const float* __restrict__ v,
                                                 const float* __restrict__ bbil,
                                                 float* __restrict__ out) {
  int p = blockIdx.x >> 8;                     // TMAX = 256
  int t = blockIdx.x & 255;
  int cnt = cursor[p];
  if (t * 64 >= cnt) return;
  __shared__ unsigned short aF[2048 * 8];      // 32 KiB A-frag tile
  __shared__ unsigned short zL[64 * 256];      // 32 KiB zdst tile (bf16, swizzled)
  __shared__ int eids[64];
  __shared__ float red[4][64];
  int tid = threadIdx.x;
  if (tid < 64) {
    int r = t * 64 + tid;
    eids[tid] = perm[p * CAP + (r < cnt ? r : cnt - 1)];
  }
  __syncthreads();
#pragma unroll
  for (int it = 0; it < 8; ++it) {
    int s = tid + it * 256;
    int kt = s >> 8, rr = (s >> 6) & 3, l = s & 63;
    int row = rr * 16 + (l & 15);
    int k0 = kt * 32 + (l >> 4) * 8;
    const float* src = zsrc + (size_t)eids[row] * ND + k0;
    const float* dsr = zdst + (size_t)eids[row] * ND + k0;
    float f[8], g[8];
    *(float4*)(f)     = *(const float4*)(src);
    *(float4*)(f + 4) = *(const float4*)(src + 4);
    *(float4*)(g)     = *(const float4*)(dsr);
    *(float4*)(g + 4) = *(const float4*)(dsr + 4);
    union { uint4 u; unsigned short h[8]; } ua, ud;
#pragma unroll
    for (int j = 0; j < 8; ++j) { ua.h[j] = f2bf(f[j]); ud.h[j] = f2bf(g[j]); }
    *(uint4*)(aF + (size_t)s * 8) = ua.u;
    unsigned int zb = (unsigned int)(row * 512 + k0 * 2) ^ (unsigned int)((row & 7) << 4);
    *(uint4*)((char*)zL + zb) = ud.u;
  }
  __syncthreads();
  int w = tid >> 6, l = tid & 63;
  const unsigned short* Cp = Cst + (size_t)p * ND * ND;
  f32x4 zero = {0.f, 0.f, 0.f, 0.f};
  f32x4 acc[4][4];
#pragma unroll
  for (int r = 0; r < 4; ++r)
#pragma unroll
    for (int c = 0; c < 4; ++c) acc[r][c] = zero;
  for (int kt = 0; kt < 8; ++kt) {
    bf16x8 a[4];
#pragma unroll
    for (int r = 0; r < 4; ++r)
      a[r] = *(const bf16x8*)(aF + (size_t)((kt * 4 + r) * 64 + l) * 8);
#pragma unroll
    for (int cl = 0; cl < 4; ++cl) {
      int c = w * 4 + cl;
      bf16x8 bb = *(const bf16x8*)(Cp + (size_t)((kt * 16 + c) * 64 + l) * 8);
#pragma unroll
      for (int r = 0; r < 4; ++r)
        acc[r][cl] = __builtin_amdgcn_mfma_f32_16x16x32_bf16(a[r], bb, acc[r][cl], 0, 0, 0);
    }
  }
  float vloc[4];
#pragma unroll
  for (int cl = 0; cl < 4; ++cl)
    vloc[cl] = v[p * ND + (w * 4 + cl) * 16 + (l & 15)];
#pragma unroll
  for (int r = 0; r < 4; ++r) {
#pragma unroll
    for (int q = 0; q < 4; ++q) {
      int row = r * 16 + ((l >> 4) * 4) + q;   // D-layout: col=l&15, row=(l>>4)*4+reg
      unsigned int swz = (unsigned int)((row & 7) << 4);
      float sv = 0.f;
#pragma unroll
      for (int cl = 0; cl < 4; ++cl) {
        int col = (w * 4 + cl) * 16 + (l & 15);
        unsigned int zb = (unsigned int)(row * 512 + col * 2) ^ swz;
        unsigned short hz = *(const unsigned short*)((const char*)zL + zb);
        float zv = __uint_as_float(((unsigned int)hz) << 16);
        sv = fmaf(acc[r][cl][q] + vloc[cl], zv, sv);
      }
      sv += __shfl_xor(sv, 1, 64);
      sv += __shfl_xor(sv, 2, 64);
      sv += __shfl_xor(sv, 4, 64);
      sv += __shfl_xor(sv, 8, 64);
      if ((l & 15) == 0) red[w][row] = sv;
    }
  }
  __syncthreads();
  if (tid < 64) {
    int gr = t * 64 + tid;
    if (gr < cnt) {
      float sc = red[0][tid] + red[1][tid] + red[2][tid] + red[3][tid] + bbil[0];
      out[eids[tid]] = sc;
    }
  }
}

extern "C" void kernel_launch(void* const* d_in, const int* in_sizes, int n_in,
                              void* d_out, int out_size, void* d_ws, size_t ws_size,
                              hipStream_t stream) {
  // setup_inputs() dict order: z_src, z_dst, W_lr, b_lr, W_bil, b_bil, lr_pair_idx
  const float* zsrc = (const float*)d_in[0];
  const float* zdst = (const float*)d_in[1];
  const float* Wlr  = (const float*)d_in[2];
  const float* blr  = (const float*)d_in[3];
  const float* Wbil = (const float*)d_in[4];
  const float* bbil = (const float*)d_in[5];
  const void*  idx  = (const void*)d_in[6];   // int32 or int64 — sniffed per block
  float* out = (float*)d_out;

  char* ws = (char*)d_ws;
  int* cursor = (int*)ws;                                  // 32 B
  int* counts = (int*)(ws + 4096);                         // 2 KiB
  int* bases  = (int*)(ws + 8192);                         // 2 KiB
  int* perm   = (int*)(ws + 16384);                        // 512 KiB
  unsigned short* WbT = (unsigned short*)(ws + 16384 + (size_t)NP * CAP * 4);            // 128 KiB
  float* v = (float*)(ws + 16384 + (size_t)NP * CAP * 4 + 131072);                       // 8 KiB
  unsigned short* Cst = (unsigned short*)(ws + 16384 + (size_t)NP * CAP * 4 + 131072 + 8192); // 1 MiB

  k_prep<<<40, 256, 0, stream>>>(Wbil, blr, WbT, v);
  k_hist<<<RBLK, 256, 0, stream>>>(idx, counts);
  k_scan<<<1, 64, 0, stream>>>(counts, bases, cursor);
  k_scatter<<<RBLK, 256, 0, stream>>>(idx, bases, perm);
  k_cpre<<<32, 256, 0, stream>>>(Wlr, WbT, Cst);
  k_main<<<NP * TMAX, 256, 0, stream>>>(zsrc, zdst, perm, cursor, Cst, v, bbil, out);
}